// Round 1
// baseline (384.060 us; speedup 1.0000x reference)
//
#include <hip/hip_runtime.h>
#include <stdint.h>
#include <stddef.h>

typedef __attribute__((ext_vector_type(8))) short short8;
typedef __attribute__((ext_vector_type(4))) float f32x4;
typedef __attribute__((ext_vector_type(4))) uint32_t u32x4;

// async global->LDS 16B (wave-uniform base + lane*16 dest; per-lane source)
#define GLD_LDS16(gsrc, ldst)                                                   \
    __builtin_amdgcn_global_load_lds(                                           \
        (const __attribute__((address_space(1))) uint32_t*)(const void*)(gsrc), \
        (__attribute__((address_space(3))) uint32_t*)(void*)(ldst), 16, 0, 0)

static __device__ __forceinline__ uint16_t bf16_rne(float f) {
    uint32_t u = __float_as_uint(f);
    uint32_t r = u + 0x7FFFu + ((u >> 16) & 1u);
    return (uint16_t)(r >> 16);
}
static __device__ __forceinline__ float bf16_f(uint16_t h) {
    return __uint_as_float(((uint32_t)h) << 16);
}

// ---------------- workspace layout (bytes) ----------------
// masks  : u16 [2048][4096]  spike bitmasks (bit t = spike at step t)
// w_in   : 3 bf16 splits of [256][4096]   (hi, mid, lo; hi+mid+lo == f32 w_in to ~2^-26)
// w_rec  : 2 bf16 splits of [256][256]
// w_out  : 2 bf16 splits of [16][256]
// iin    : f32 [20480][256]  = enc @ w_in.T for all (b,t), row m = b*10+t
#define OFF_MASKS 0u
#define SZ_MASKS  (2048u * 4096u * 2u)
#define OFF_WIN   (OFF_MASKS + SZ_MASKS)
#define SZ_WIN1   (256u * 4096u * 2u)
#define OFF_WREC  (OFF_WIN + 3u * SZ_WIN1)
#define SZ_WREC1  (256u * 256u * 2u)
#define OFF_WOUT  (OFF_WREC + 2u * SZ_WREC1)
#define SZ_WOUT1  (16u * 256u * 2u)
#define OFF_IIN   (OFF_WOUT + 2u * SZ_WOUT1)
// total = 23347200 + 20971520 = 44318720 bytes (~42.3 MiB)

// ---------------- kernel 1: encoder -> 10-bit spike masks ----------------
__global__ __launch_bounds__(256) void k_prep(const float* __restrict__ x,
                                              uint16_t* __restrict__ masks) {
    int g = blockIdx.x * 256 + threadIdx.x;   // grid covers 2048*2048 exactly
    int b = g >> 11, s = g & 2047;
    float q = 50.0f * x[g];
    float c = fabsf(q);                        // = relu(50x) or relu(-50x), the active half
    float v = 0.0f;
    uint32_t m = 0u;
    #pragma unroll
    for (int t = 0; t < 10; ++t) {
        v = v + 0.1f * ((0.0f - v) + c);       // LIF encoder dynamics (exact ref expr)
        if (v > 1.0f) { m |= (1u << t); v = 0.0f; }
    }
    masks[(size_t)b * 4096 + s]        = (q > 0.0f) ? (uint16_t)m : (uint16_t)0;
    masks[(size_t)b * 4096 + 2048 + s] = (q < 0.0f) ? (uint16_t)m : (uint16_t)0;
}

// ---------------- kernel 2: f32 -> bf16 split weights ----------------
__global__ __launch_bounds__(256) void k_wsplit(const float* __restrict__ win,
                                                const float* __restrict__ wrec,
                                                const float* __restrict__ wout,
                                                uint16_t* __restrict__ win_s,
                                                uint16_t* __restrict__ wrec_s,
                                                uint16_t* __restrict__ wout_s) {
    int g = blockIdx.x * 256 + threadIdx.x;
    if (g < 1048576) {
        float w = win[g];
        uint16_t h = bf16_rne(w);
        float r1 = w - bf16_f(h);
        uint16_t md = bf16_rne(r1);
        float r2 = r1 - bf16_f(md);
        win_s[g]            = h;
        win_s[1048576 + g]  = md;
        win_s[2097152 + g]  = bf16_rne(r2);
    } else if (g < 1114112) {
        int i = g - 1048576;
        float w = wrec[i];
        uint16_t h = bf16_rne(w);
        float r1 = w - bf16_f(h);
        wrec_s[i]         = h;
        wrec_s[65536 + i] = bf16_rne(r1);
    } else if (g < 1118208) {
        int i = g - 1114112;
        float w = wout[i];
        uint16_t h = bf16_rne(w);
        float r1 = w - bf16_f(h);
        wout_s[i]        = h;
        wout_s[4096 + i] = bf16_rne(r1);
    }
}

// ---------------- kernel 3: I_in = enc @ w_in.T  (binary-A split GEMM) ----------------
// M=20480 (row m = b*10+t), K=4096, N=256. BM=80, BN=128 -> 512 blocks (2/CU).
// 4 waves; wave owns n-range 32 (2 n-frags), all 5 m-frags. Split loop outermost.
__global__ __launch_bounds__(256) void k_gemm(const uint16_t* __restrict__ masks,
                                              const uint16_t* __restrict__ wsp,
                                              float* __restrict__ iin) {
    __shared__ uint16_t Abuf[2][80 * 64];    // 10 KB each, XOR-swizzled rows of 128B
    __shared__ uint16_t Bbuf[2][128 * 64];   // 16 KB each, swizzle via pre-swizzled source
    const int tid = threadIdx.x;
    const int lane = tid & 63;
    const int wid = tid >> 6;
    const int l15 = lane & 15;
    const int lq = lane >> 4;
    const int Mtile = blockIdx.x >> 1;
    const int Ntile = blockIdx.x & 1;
    const int M0 = Mtile * 80;

    // expand spike bits -> bf16 {0,1} A-tile for K-step kk into Abuf[ab]
    auto expandA = [&](int kk, int ab) {
        for (int c = tid; c < 320; c += 256) {     // 80 rows x 4 k-groups of 16
            int r = c >> 2;
            int k16 = (c & 3) << 4;
            uint32_t m = (uint32_t)(M0 + r);
            uint32_t b = (m * 52429u) >> 19;        // m / 10
            uint32_t t = m - b * 10u;
            const u32x4* mp = (const u32x4*)(masks + (size_t)b * 4096 + (size_t)(kk * 64 + k16));
            u32x4 q0 = mp[0];
            u32x4 q1 = mp[1];
            u32x4 o0, o1;
            #pragma unroll
            for (int j = 0; j < 4; ++j) {
                uint32_t x0 = q0[j] >> t;
                uint32_t x1 = q1[j] >> t;
                // bit0 -> bf16 1.0 in low half, bit16 -> bf16 1.0 in high half
                o0[j] = (x0 & 1u) * 0x3F80u + (x0 & 0x10000u) * 0x3F80u;
                o1[j] = (x1 & 1u) * 0x3F80u + (x1 & 0x10000u) * 0x3F80u;
            }
            uint32_t swz = (uint32_t)((r & 7) << 4);
            uint32_t base = (uint32_t)(r * 128 + (k16 << 1));
            char* dst = (char*)Abuf[ab];
            *(u32x4*)(dst + (base ^ swz)) = o0;
            *(u32x4*)(dst + ((base + 16u) ^ swz)) = o1;
        }
    };

    // stage B tile [128 n][64 k] bf16 for (kk, split s) into Bbuf[bb]
    // linear LDS dest + inverse-swizzled per-lane SOURCE column (rule #21)
    auto stageB = [&](int kk, int s, int bb) {
        const char* src = (const char*)wsp + (size_t)s * 2097152u;
        char* dst = (char*)Bbuf[bb];
        #pragma unroll
        for (int p = 0; p < 4; ++p) {
            int c = (p << 8) + tid;                 // chunk 0..1023, wave-contiguous
            int n = c >> 3;
            uint32_t off = (uint32_t)((c & 7) << 4);
            uint32_t so = (uint32_t)(Ntile * 128 + n) * 8192u + (uint32_t)(kk << 7)
                        + (off ^ (uint32_t)((n & 7) << 4));
            GLD_LDS16(src + so, dst + (size_t)c * 16u);
        }
    };

    f32x4 acc[5][2];
    #pragma unroll
    for (int mt = 0; mt < 5; ++mt)
        #pragma unroll
        for (int nt = 0; nt < 2; ++nt)
            #pragma unroll
            for (int q = 0; q < 4; ++q) acc[mt][nt][q] = 0.0f;

    expandA(0, 0);
    stageB(0, 0, 0);
    __syncthreads();

    int it = 0;
    for (int s = 0; s < 3; ++s) {                  // split outermost: B set is L2-resident per phase
        for (int kk = 0; kk < 64; ++kk, ++it) {
            const int ab = kk & 1;
            const int bb = it & 1;
            if (it + 1 < 192) {
                int nkk = (kk == 63) ? 0 : kk + 1;
                int ns = (kk == 63) ? s + 1 : s;
                stageB(nkk, ns, bb ^ 1);
                expandA(nkk, (kk + 1) & 1);
            }
            short8 af[5][2];
            short8 bf[2][2];
            const char* Ab = (const char*)Abuf[ab];
            const char* Bp = (const char*)Bbuf[bb];
            #pragma unroll
            for (int mt = 0; mt < 5; ++mt)
                #pragma unroll
                for (int kt = 0; kt < 2; ++kt) {
                    int row = mt * 16 + l15;
                    uint32_t byte = (uint32_t)(row * 128)
                                  + ((uint32_t)((kt << 6) + (lq << 4)) ^ (uint32_t)((row & 7) << 4));
                    af[mt][kt] = *(const short8*)(Ab + byte);
                }
            #pragma unroll
            for (int nt = 0; nt < 2; ++nt)
                #pragma unroll
                for (int kt = 0; kt < 2; ++kt) {
                    int n = (wid << 5) + nt * 16 + l15;
                    uint32_t byte = (uint32_t)(n * 128)
                                  + ((uint32_t)((kt << 6) + (lq << 4)) ^ (uint32_t)((n & 7) << 4));
                    bf[nt][kt] = *(const short8*)(Bp + byte);
                }
            #pragma unroll
            for (int kt = 0; kt < 2; ++kt)
                #pragma unroll
                for (int mt = 0; mt < 5; ++mt)
                    #pragma unroll
                    for (int nt = 0; nt < 2; ++nt)
                        acc[mt][nt] = __builtin_amdgcn_mfma_f32_16x16x32_bf16(
                            af[mt][kt], bf[nt][kt], acc[mt][nt], 0, 0, 0);
            __syncthreads();
        }
    }

    #pragma unroll
    for (int mt = 0; mt < 5; ++mt)
        #pragma unroll
        for (int nt = 0; nt < 2; ++nt)
            #pragma unroll
            for (int i = 0; i < 4; ++i) {
                int gm = M0 + mt * 16 + (lq << 2) + i;               // C: row=(lane>>4)*4+i
                int h = Ntile * 128 + (wid << 5) + nt * 16 + l15;    //    col=lane&15
                iin[(size_t)gm * 256 + h] = acc[mt][nt][i];
            }
}

// ---------------- kernel 4: recurrent scan + LI readout + softmax ----------------
// 128 blocks x 16 batch rows; per-row dynamics are independent -> no grid sync.
__global__ __launch_bounds__(256) void k_scan(const float* __restrict__ iin,
                                              const uint16_t* __restrict__ wrec_s,
                                              const uint16_t* __restrict__ wout_s,
                                              float* __restrict__ out) {
    __shared__ uint16_t Z[2][16 * 256];     // z spikes bf16, ping-pong, swizzled rows 512B
    __shared__ uint16_t Bb[2][256 * 64];    // streamed w_rec split tiles [n=256][k=64]
    __shared__ uint16_t WO[2][16 * 256];    // resident w_out splits [a=16][h=256]
    const int tid = threadIdx.x;
    const int lane = tid & 63;
    const int wid = tid >> 6;
    const int l15 = lane & 15;
    const int lq = lane >> 4;
    const int b0 = blockIdx.x << 4;

    // stage w_out splits (swizzled)
    #pragma unroll
    for (int s = 0; s < 2; ++s) {
        #pragma unroll
        for (int p = 0; p < 2; ++p) {
            int c = (p << 8) + tid;
            int n = c >> 5;
            uint32_t off = (uint32_t)((c & 31) << 4);
            u32x4 v = *(const u32x4*)((const char*)(wout_s + (size_t)s * 4096) + (size_t)n * 512 + off);
            *(u32x4*)((char*)WO[s] + (uint32_t)(n * 512) + (off ^ (uint32_t)((n & 7) << 4))) = v;
        }
    }
    // z_{-1} = 0
    #pragma unroll
    for (int p = 0; p < 8; ++p) ((uint32_t*)Z[0])[(p << 8) + tid] = 0u;

    // stream w_rec split tiles; tile stream index g = t*8 + j, tile depends on j=g&7 only
    auto stageBrec = [&](int g, int db) {
        int jj = g & 7;
        int sp = jj >> 2;
        int ks = jj & 3;
        const char* src = (const char*)(wrec_s + (size_t)sp * 65536);
        char* dst = (char*)Bb[db];
        #pragma unroll
        for (int p = 0; p < 8; ++p) {
            int c = (p << 8) + tid;
            int n = c >> 3;
            uint32_t off = (uint32_t)((c & 7) << 4);
            uint32_t so = (uint32_t)(n * 512) + (uint32_t)(ks << 7) + (off ^ (uint32_t)((n & 7) << 4));
            GLD_LDS16(src + so, dst + (size_t)c * 16);
        }
    };
    stageBrec(0, 0);

    // state: thread holds (b = lq*4+r, h = wid*64 + nf*16 + l15), nf=0..3, r=0..3
    float vst[4][4], ist[4][4];
    #pragma unroll
    for (int nf = 0; nf < 4; ++nf)
        #pragma unroll
        for (int r = 0; r < 4; ++r) { vst[nf][r] = 0.0f; ist[nf][r] = 0.0f; }
    float io_[4] = {0.f, 0.f, 0.f, 0.f};
    float vo_[4] = {0.f, 0.f, 0.f, 0.f};
    float mm[4] = {-1e30f, -1e30f, -1e30f, -1e30f};

    __syncthreads();

    #pragma unroll 1
    for (int t = 0; t < 10; ++t) {
        const int pp = t & 1;                       // z_old buffer; z_new -> pp^1
        f32x4 acc[4];
        #pragma unroll
        for (int nf = 0; nf < 4; ++nf) {
            #pragma unroll
            for (int r = 0; r < 4; ++r) {
                float vv = vst[nf][r];
                float ii = ist[nf][r];
                float vd = vv + 0.1f * ((0.0f - vv) + ii);   // v_dec (old i)
                bool z = (vd > 1.0f);
                vst[nf][r] = z ? 0.0f : vd;
                int brow = (lq << 2) + r;
                int h = (wid << 6) + (nf << 4) + l15;
                uint32_t byte = (uint32_t)(brow * 512)
                              + ((uint32_t)(h << 1) ^ (uint32_t)((brow & 7) << 4));
                *(uint16_t*)((char*)Z[pp ^ 1] + byte) = z ? (uint16_t)0x3F80u : (uint16_t)0u;
                float I = iin[(size_t)((b0 + brow) * 10 + t) * 256 + h];
                acc[nf][r] = 0.8f * ii + I;                  // i_dec + input current
            }
        }
        __syncthreads();
        // i += z_old @ w_rec.T  : K_eff = 512 (2 splits x 256), 8 K-steps of 64
        for (int j = 0; j < 8; ++j) {
            int g = (t << 3) + j;
            if (g + 1 < 80) stageBrec(g + 1, (g + 1) & 1);
            int ks = j & 3;
            short8 az[2];
            #pragma unroll
            for (int kt = 0; kt < 2; ++kt) {
                int kb = (ks << 7) + (kt << 6) + (lq << 4);   // k byte offset
                uint32_t byte = (uint32_t)(l15 * 512)
                              + ((uint32_t)kb ^ (uint32_t)((l15 & 7) << 4));
                az[kt] = *(const short8*)((const char*)Z[pp] + byte);
            }
            const char* Bp = (const char*)Bb[g & 1];
            #pragma unroll
            for (int nf = 0; nf < 4; ++nf) {
                int n = (wid << 6) + (nf << 4) + l15;
                #pragma unroll
                for (int kt = 0; kt < 2; ++kt) {
                    uint32_t byte = (uint32_t)(n * 128)
                                  + ((uint32_t)((kt << 6) + (lq << 4)) ^ (uint32_t)((n & 7) << 4));
                    short8 bw = *(const short8*)(Bp + byte);
                    acc[nf] = __builtin_amdgcn_mfma_f32_16x16x32_bf16(az[kt], bw, acc[nf], 0, 0, 0);
                }
            }
            __syncthreads();
        }
        #pragma unroll
        for (int nf = 0; nf < 4; ++nf)
            #pragma unroll
            for (int r = 0; r < 4; ++r) ist[nf][r] = acc[nf][r];

        // LI readout on wave 0: io_new = 0.8*io + z_new @ w_out.T ; vo_new uses OLD io
        if (wid == 0) {
            f32x4 aio;
            #pragma unroll
            for (int r = 0; r < 4; ++r) aio[r] = 0.8f * io_[r];
            #pragma unroll
            for (int s = 0; s < 2; ++s) {
                #pragma unroll
                for (int kc = 0; kc < 8; ++kc) {
                    int kb = (kc << 6) + (lq << 4);
                    uint32_t byte = (uint32_t)(l15 * 512)
                                  + ((uint32_t)kb ^ (uint32_t)((l15 & 7) << 4));
                    short8 azn = *(const short8*)((const char*)Z[pp ^ 1] + byte);
                    short8 bwo = *(const short8*)((const char*)WO[s] + byte);
                    aio = __builtin_amdgcn_mfma_f32_16x16x32_bf16(azn, bwo, aio, 0, 0, 0);
                }
            }
            #pragma unroll
            for (int r = 0; r < 4; ++r) {
                float von = vo_[r] + 0.1f * ((0.0f - vo_[r]) + io_[r]);
                io_[r] = aio[r];
                vo_[r] = von;
                mm[r] = fmaxf(mm[r], von);
            }
        }
    }

    // fused: m = max_t(vo); nan->0; softmax over A=16 (16-lane groups)
    if (wid == 0) {
        #pragma unroll
        for (int r = 0; r < 4; ++r) {
            float mv = mm[r];
            if (mv != mv) mv = 0.0f;
            float mx = mv;
            #pragma unroll
            for (int d = 1; d < 16; d <<= 1) mx = fmaxf(mx, __shfl_xor(mx, d));
            float e = __expf(mv - mx);
            float ss = e;
            #pragma unroll
            for (int d = 1; d < 16; d <<= 1) ss += __shfl_xor(ss, d);
            out[(size_t)(b0 + (lq << 2) + r) * 16 + l15] = e / ss;
        }
    }
}

extern "C" void kernel_launch(void* const* d_in, const int* in_sizes, int n_in,
                              void* d_out, int out_size, void* d_ws, size_t ws_size,
                              hipStream_t stream) {
    (void)in_sizes; (void)n_in; (void)out_size; (void)ws_size;
    const float* x     = (const float*)d_in[0];
    const float* w_in  = (const float*)d_in[1];
    const float* w_rec = (const float*)d_in[2];
    const float* w_out = (const float*)d_in[3];
    float* out = (float*)d_out;
    char* ws = (char*)d_ws;
    uint16_t* masks  = (uint16_t*)(ws + OFF_MASKS);
    uint16_t* win_s  = (uint16_t*)(ws + OFF_WIN);
    uint16_t* wrec_s = (uint16_t*)(ws + OFF_WREC);
    uint16_t* wout_s = (uint16_t*)(ws + OFF_WOUT);
    float* iin = (float*)(ws + OFF_IIN);

    k_prep  <<<dim3(16384), dim3(256), 0, stream>>>(x, masks);
    k_wsplit<<<dim3(4368),  dim3(256), 0, stream>>>(w_in, w_rec, w_out, win_s, wrec_s, wout_s);
    k_gemm  <<<dim3(512),   dim3(256), 0, stream>>>(masks, win_s, iin);
    k_scan  <<<dim3(128),   dim3(256), 0, stream>>>(iin, wrec_s, wout_s, out);
}

// Round 4
// 245.707 us; speedup vs baseline: 1.5631x; 1.5631x over previous
//
#include <hip/hip_runtime.h>
#include <stdint.h>
#include <stddef.h>

typedef __attribute__((ext_vector_type(8))) short short8;
typedef __attribute__((ext_vector_type(4))) float f32x4;
typedef __attribute__((ext_vector_type(4))) uint32_t u32x4;

// async global->LDS 16B (wave-uniform base + lane*16 dest; per-lane source)
#define GLD_LDS16(gsrc, ldst)                                                   \
    __builtin_amdgcn_global_load_lds(                                           \
        (const __attribute__((address_space(1))) uint32_t*)(const void*)(gsrc), \
        (__attribute__((address_space(3))) uint32_t*)(void*)(ldst), 16, 0, 0)

static __device__ __forceinline__ uint16_t bf16_rne(float f) {
    uint32_t u = __float_as_uint(f);
    uint32_t r = u + 0x7FFFu + ((u >> 16) & 1u);
    return (uint16_t)(r >> 16);
}
static __device__ __forceinline__ float bf16_f(uint16_t h) {
    return __uint_as_float(((uint32_t)h) << 16);
}

// ---------------- workspace layout (bytes) ----------------
#define OFF_MASKS 0u
#define SZ_MASKS  (2048u * 4096u * 2u)
#define OFF_WIN   (OFF_MASKS + SZ_MASKS)
#define SZ_WIN1   (256u * 4096u * 2u)
#define OFF_WREC  (OFF_WIN + 3u * SZ_WIN1)
#define SZ_WREC1  (256u * 256u * 2u)
#define OFF_WOUT  (OFF_WREC + 2u * SZ_WREC1)
#define SZ_WOUT1  (16u * 256u * 2u)
#define OFF_IIN   (OFF_WOUT + 2u * SZ_WOUT1)

// ---------------- kernel 1: encoder -> 10-bit spike masks ----------------
__global__ __launch_bounds__(256) void k_prep(const float* __restrict__ x,
                                              uint16_t* __restrict__ masks) {
    int g = blockIdx.x * 256 + threadIdx.x;
    int b = g >> 11, s = g & 2047;
    float q = 50.0f * x[g];
    float c = fabsf(q);
    float v = 0.0f;
    uint32_t m = 0u;
    #pragma unroll
    for (int t = 0; t < 10; ++t) {
        v = v + 0.1f * ((0.0f - v) + c);
        if (v > 1.0f) { m |= (1u << t); v = 0.0f; }
    }
    masks[(size_t)b * 4096 + s]        = (q > 0.0f) ? (uint16_t)m : (uint16_t)0;
    masks[(size_t)b * 4096 + 2048 + s] = (q < 0.0f) ? (uint16_t)m : (uint16_t)0;
}

// ---------------- kernel 2: f32 -> bf16 split weights ----------------
__global__ __launch_bounds__(256) void k_wsplit(const float* __restrict__ win,
                                                const float* __restrict__ wrec,
                                                const float* __restrict__ wout,
                                                uint16_t* __restrict__ win_s,
                                                uint16_t* __restrict__ wrec_s,
                                                uint16_t* __restrict__ wout_s) {
    int g = blockIdx.x * 256 + threadIdx.x;
    if (g < 1048576) {
        float w = win[g];
        uint16_t h = bf16_rne(w);
        float r1 = w - bf16_f(h);
        uint16_t md = bf16_rne(r1);
        float r2 = r1 - bf16_f(md);
        win_s[g]            = h;
        win_s[1048576 + g]  = md;
        win_s[2097152 + g]  = bf16_rne(r2);
    } else if (g < 1114112) {
        int i = g - 1048576;
        float w = wrec[i];
        uint16_t h = bf16_rne(w);
        float r1 = w - bf16_f(h);
        wrec_s[i]         = h;
        wrec_s[65536 + i] = bf16_rne(r1);
    } else if (g < 1118208) {
        int i = g - 1114112;
        float w = wout[i];
        uint16_t h = bf16_rne(w);
        float r1 = w - bf16_f(h);
        wout_s[i]        = h;
        wout_s[4096 + i] = bf16_rne(r1);
    }
}

// ---------------- kernel 3: I_in = enc @ w_in.T (binary-A split GEMM) -------
// M=20480, K=4096, N=256. BM=80, BN=128 -> 512 blocks (2/CU). kk-outer,
// split-inner; 3-buffer B ring with counted vmcnt; masks prefetched to regs
// one phase early so their consumption never drains the B-stage loads.
__global__ __launch_bounds__(256) void k_gemm(const uint16_t* __restrict__ masks,
                                              const uint16_t* __restrict__ wsp,
                                              float* __restrict__ iin) {
    __shared__ uint16_t Abuf[2][80 * 64];    // 10 KB x2, XOR-swizzled 128B rows
    __shared__ uint16_t Bbuf[3][128 * 64];   // 16 KB x3 ring
    const int tid = threadIdx.x;
    const int lane = tid & 63;
    const int wid = tid >> 6;
    const int l15 = lane & 15;
    const int lq = lane >> 4;
    const int Mtile = blockIdx.x >> 1;
    const int Ntile = blockIdx.x & 1;
    const int M0 = Mtile * 80;

    const int c0 = tid;          // chunk 0 (always)
    const int c1 = tid + 256;    // chunk 1 (tid<64 only)

    uint32_t mq[2][8];           // mask regs: 2 chunks x 8 u32

    auto loadMasks = [&](int kk) {
        {
            int r = c0 >> 2, k16 = (c0 & 3) << 4;
            uint32_t m = (uint32_t)(M0 + r);
            uint32_t b = (m * 52429u) >> 19;        // m/10
            const u32x4* mp = (const u32x4*)(masks + (size_t)b * 4096 + (size_t)(kk * 64 + k16));
            u32x4 q0 = mp[0], q1 = mp[1];
            #pragma unroll
            for (int j = 0; j < 4; ++j) { mq[0][j] = q0[j]; mq[0][4 + j] = q1[j]; }
        }
        if (c1 < 320) {
            int r = c1 >> 2, k16 = (c1 & 3) << 4;
            uint32_t m = (uint32_t)(M0 + r);
            uint32_t b = (m * 52429u) >> 19;
            const u32x4* mp = (const u32x4*)(masks + (size_t)b * 4096 + (size_t)(kk * 64 + k16));
            u32x4 q0 = mp[0], q1 = mp[1];
            #pragma unroll
            for (int j = 0; j < 4; ++j) { mq[1][j] = q0[j]; mq[1][4 + j] = q1[j]; }
        }
    };

    auto expandWrite = [&](int ab) {          // pure VALU + ds_write (no loads)
        #pragma unroll
        for (int ci = 0; ci < 2; ++ci) {
            int c = (ci == 0) ? c0 : c1;
            if (c >= 320) break;
            int r = c >> 2, k16 = (c & 3) << 4;
            uint32_t m = (uint32_t)(M0 + r);
            uint32_t b = (m * 52429u) >> 19;
            uint32_t t = m - b * 10u;
            u32x4 o0, o1;
            #pragma unroll
            for (int j = 0; j < 4; ++j) {
                uint32_t x0 = mq[ci][j] >> t;
                uint32_t x1 = mq[ci][4 + j] >> t;
                o0[j] = (x0 & 1u) * 0x3F80u + (x0 & 0x10000u) * 0x3F80u;
                o1[j] = (x1 & 1u) * 0x3F80u + (x1 & 0x10000u) * 0x3F80u;
            }
            uint32_t swz = (uint32_t)((r & 7) << 4);
            uint32_t base = (uint32_t)(r * 128 + (k16 << 1));
            char* dst = (char*)Abuf[ab];
            *(u32x4*)(dst + (base ^ swz)) = o0;
            *(u32x4*)(dst + ((base + 16u) ^ swz)) = o1;
        }
    };

    auto stageB = [&](int kk, int s, uint16_t* bufp) {
        const char* src = (const char*)wsp + (size_t)s * 2097152u;
        char* dst = (char*)bufp;
        #pragma unroll
        for (int p = 0; p < 4; ++p) {
            int c = (p << 8) + tid;
            int n = c >> 3;
            uint32_t off = (uint32_t)((c & 7) << 4);
            uint32_t so = (uint32_t)(Ntile * 128 + n) * 8192u + (uint32_t)(kk << 7)
                        + (off ^ (uint32_t)((n & 7) << 4));
            GLD_LDS16(src + so, dst + (size_t)c * 16u);
        }
    };

    short8 af[5][2];
    f32x4 acc[5][2];
    #pragma unroll
    for (int mt = 0; mt < 5; ++mt)
        #pragma unroll
        for (int nt = 0; nt < 2; ++nt)
            #pragma unroll
            for (int q = 0; q < 4; ++q) acc[mt][nt][q] = 0.0f;

    auto readA = [&](int ab) {
        #pragma unroll
        for (int mt = 0; mt < 5; ++mt)
            #pragma unroll
            for (int kt = 0; kt < 2; ++kt) {
                int row = mt * 16 + l15;
                uint32_t byte = (uint32_t)(row * 128)
                              + ((uint32_t)((kt << 6) + (lq << 4)) ^ (uint32_t)((row & 7) << 4));
                af[mt][kt] = *(const short8*)((const char*)Abuf[ab] + byte);
            }
    };
    auto mfmaPhase = [&](const uint16_t* Bpp) {
        short8 bf[2][2];
        #pragma unroll
        for (int nt = 0; nt < 2; ++nt)
            #pragma unroll
            for (int kt = 0; kt < 2; ++kt) {
                int n = (wid << 5) + nt * 16 + l15;
                uint32_t byte = (uint32_t)(n * 128)
                              + ((uint32_t)((kt << 6) + (lq << 4)) ^ (uint32_t)((n & 7) << 4));
                bf[nt][kt] = *(const short8*)((const char*)Bpp + byte);
            }
        __builtin_amdgcn_s_setprio(1);
        #pragma unroll
        for (int kt = 0; kt < 2; ++kt)
            #pragma unroll
            for (int mt = 0; mt < 5; ++mt)
                #pragma unroll
                for (int nt = 0; nt < 2; ++nt)
                    acc[mt][nt] = __builtin_amdgcn_mfma_f32_16x16x32_bf16(
                        af[mt][kt], bf[nt][kt], acc[mt][nt], 0, 0, 0);
        __builtin_amdgcn_s_setprio(0);
    };

    // prologue: A(0) expanded, B(kk=0,s=0) staged into ring slot 0
    loadMasks(0);
    expandWrite(0);
    stageB(0, 0, Bbuf[0]);

    #pragma unroll 1
    for (int kk = 0; kk < 64; ++kk) {
        const int ab = kk & 1;
        const bool more = (kk < 63);
        // ---- phase s==0: reads Bbuf[0]; stages Bbuf[1]; prefetch masks ----
        if (more) loadMasks(kk + 1);
        __builtin_amdgcn_sched_barrier(0);           // masks issue before stage
        stageB(kk, 1, Bbuf[1]);
        if (more) asm volatile("s_waitcnt vmcnt(6) lgkmcnt(0)" ::: "memory");
        else      asm volatile("s_waitcnt vmcnt(4) lgkmcnt(0)" ::: "memory");
        __builtin_amdgcn_s_barrier();
        __builtin_amdgcn_sched_barrier(0);
        readA(ab);
        mfmaPhase(Bbuf[0]);
        // ---- phase s==1: reads Bbuf[1]; stages Bbuf[2]; expand A(kk+1) ----
        if (more) expandWrite(ab ^ 1);               // VALU-only, masks in regs
        __builtin_amdgcn_sched_barrier(0);
        stageB(kk, 2, Bbuf[2]);
        asm volatile("s_waitcnt vmcnt(4) lgkmcnt(0)" ::: "memory");
        __builtin_amdgcn_s_barrier();
        __builtin_amdgcn_sched_barrier(0);
        mfmaPhase(Bbuf[1]);
        // ---- phase s==2: reads Bbuf[2]; stages Bbuf[0] for kk+1 ----------
        if (more) {
            stageB(kk + 1, 0, Bbuf[0]);
            asm volatile("s_waitcnt vmcnt(4) lgkmcnt(0)" ::: "memory");
        } else {
            asm volatile("s_waitcnt vmcnt(0) lgkmcnt(0)" ::: "memory");
        }
        __builtin_amdgcn_s_barrier();
        __builtin_amdgcn_sched_barrier(0);
        mfmaPhase(Bbuf[2]);
    }

    #pragma unroll
    for (int mt = 0; mt < 5; ++mt)
        #pragma unroll
        for (int nt = 0; nt < 2; ++nt)
            #pragma unroll
            for (int i = 0; i < 4; ++i) {
                int gm = M0 + mt * 16 + (lq << 2) + i;
                int h = Ntile * 128 + (wid << 5) + nt * 16 + l15;
                iin[(size_t)gm * 256 + h] = acc[mt][nt][i];
            }
}

// ---------------- kernel 4: recurrent scan + LI readout + softmax ----------
__global__ __launch_bounds__(256) void k_scan(const float* __restrict__ iin,
                                              const uint16_t* __restrict__ wrec_s,
                                              const uint16_t* __restrict__ wout_s,
                                              float* __restrict__ out) {
    __shared__ uint16_t Z[2][16 * 256];     // 16 KB
    __shared__ uint16_t Bb[3][256 * 64];    // 96 KB ring of w_rec tiles
    __shared__ uint16_t WO[2][16 * 256];    // 16 KB resident w_out splits
    const int tid = threadIdx.x;
    const int lane = tid & 63;
    const int wid = tid >> 6;
    const int l15 = lane & 15;
    const int lq = lane >> 4;
    const int b0 = blockIdx.x << 4;

    #pragma unroll
    for (int s = 0; s < 2; ++s) {
        #pragma unroll
        for (int p = 0; p < 2; ++p) {
            int c = (p << 8) + tid;
            int n = c >> 5;
            uint32_t off = (uint32_t)((c & 31) << 4);
            u32x4 v = *(const u32x4*)((const char*)(wout_s + (size_t)s * 4096) + (size_t)n * 512 + off);
            *(u32x4*)((char*)WO[s] + (uint32_t)(n * 512) + (off ^ (uint32_t)((n & 7) << 4))) = v;
        }
    }
    #pragma unroll
    for (int p = 0; p < 8; ++p) ((uint32_t*)Z[0])[(p << 8) + tid] = 0u;

    auto stageBrec = [&](int g, int db) {
        int jj = g & 7;
        int sp = jj >> 2;
        int ks = jj & 3;
        const char* src = (const char*)(wrec_s + (size_t)sp * 65536);
        char* dst = (char*)Bb[db];
        #pragma unroll
        for (int p = 0; p < 8; ++p) {
            int c = (p << 8) + tid;
            int n = c >> 3;
            uint32_t off = (uint32_t)((c & 7) << 4);
            uint32_t so = (uint32_t)(n * 512) + (uint32_t)(ks << 7) + (off ^ (uint32_t)((n & 7) << 4));
            GLD_LDS16(src + so, dst + (size_t)c * 16);
        }
    };
    stageBrec(0, 0);
    asm volatile("s_waitcnt lgkmcnt(0)" ::: "memory");   // WO/Z writes visible; keep stage in flight
    __builtin_amdgcn_s_barrier();

    float vst[4][4], ist[4][4];
    #pragma unroll
    for (int nf = 0; nf < 4; ++nf)
        #pragma unroll
        for (int r = 0; r < 4; ++r) { vst[nf][r] = 0.0f; ist[nf][r] = 0.0f; }
    float io_[4] = {0.f, 0.f, 0.f, 0.f};
    float vo_[4] = {0.f, 0.f, 0.f, 0.f};
    float mm[4] = {-1e30f, -1e30f, -1e30f, -1e30f};

    int cur = 0;
    #pragma unroll 1
    for (int t = 0; t < 10; ++t) {
        const int pp = t & 1;
        f32x4 acc[4];
        #pragma unroll
        for (int nf = 0; nf < 4; ++nf) {
            #pragma unroll
            for (int r = 0; r < 4; ++r) {
                float vv = vst[nf][r];
                float ii = ist[nf][r];
                float vd = vv + 0.1f * ((0.0f - vv) + ii);
                bool z = (vd > 1.0f);
                vst[nf][r] = z ? 0.0f : vd;
                int brow = (lq << 2) + r;
                int h = (wid << 6) + (nf << 4) + l15;
                uint32_t byte = (uint32_t)(brow * 512)
                              + ((uint32_t)(h << 1) ^ (uint32_t)((brow & 7) << 4));
                *(uint16_t*)((char*)Z[pp ^ 1] + byte) = z ? (uint16_t)0x3F80u : (uint16_t)0u;
                float I = iin[(size_t)((b0 + brow) * 10 + t) * 256 + h];
                acc[nf][r] = 0.8f * ii + I;
            }
        }
        // i += z_old @ w_rec.T : 8 K-steps of 64 over (2 splits x 256)
        for (int j = 0; j < 8; ++j) {
            int g = (t << 3) + j;
            int nxt = (cur == 2) ? 0 : cur + 1;
            if (g + 1 < 80) {
                stageBrec(g + 1, nxt);
                asm volatile("s_waitcnt vmcnt(8) lgkmcnt(0)" ::: "memory");
            } else {
                asm volatile("s_waitcnt vmcnt(0) lgkmcnt(0)" ::: "memory");
            }
            __builtin_amdgcn_s_barrier();
            __builtin_amdgcn_sched_barrier(0);
            int ks = j & 3;
            short8 az[2];
            #pragma unroll
            for (int kt = 0; kt < 2; ++kt) {
                int kb = (ks << 7) + (kt << 6) + (lq << 4);
                uint32_t byte = (uint32_t)(l15 * 512)
                              + ((uint32_t)kb ^ (uint32_t)((l15 & 7) << 4));
                az[kt] = *(const short8*)((const char*)Z[pp] + byte);
            }
            const char* Bp = (const char*)Bb[cur];
            __builtin_amdgcn_s_setprio(1);
            #pragma unroll
            for (int nf = 0; nf < 4; ++nf) {
                int n = (wid << 6) + (nf << 4) + l15;
                #pragma unroll
                for (int kt = 0; kt < 2; ++kt) {
                    uint32_t byte = (uint32_t)(n * 128)
                                  + ((uint32_t)((kt << 6) + (lq << 4)) ^ (uint32_t)((n & 7) << 4));
                    short8 bw = *(const short8*)(Bp + byte);
                    acc[nf] = __builtin_amdgcn_mfma_f32_16x16x32_bf16(az[kt], bw, acc[nf], 0, 0, 0);
                }
            }
            __builtin_amdgcn_s_setprio(0);
            cur = nxt;
        }
        #pragma unroll
        for (int nf = 0; nf < 4; ++nf)
            #pragma unroll
            for (int r = 0; r < 4; ++r) ist[nf][r] = acc[nf][r];

        if (wid == 0) {
            f32x4 aio;
            #pragma unroll
            for (int r = 0; r < 4; ++r) aio[r] = 0.8f * io_[r];
            #pragma unroll
            for (int s = 0; s < 2; ++s) {
                #pragma unroll
                for (int kc = 0; kc < 8; ++kc) {
                    int kb = (kc << 6) + (lq << 4);
                    uint32_t byte = (uint32_t)(l15 * 512)
                                  + ((uint32_t)kb ^ (uint32_t)((l15 & 7) << 4));
                    short8 azn = *(const short8*)((const char*)Z[pp ^ 1] + byte);
                    short8 bwo = *(const short8*)((const char*)WO[s] + byte);
                    aio = __builtin_amdgcn_mfma_f32_16x16x32_bf16(azn, bwo, aio, 0, 0, 0);
                }
            }
            #pragma unroll
            for (int r = 0; r < 4; ++r) {
                float von = vo_[r] + 0.1f * ((0.0f - vo_[r]) + io_[r]);
                io_[r] = aio[r];
                vo_[r] = von;
                mm[r] = fmaxf(mm[r], von);
            }
        }
        __builtin_amdgcn_s_barrier();   // end-of-t: protect Z buffers for next state phase
    }

    if (wid == 0) {
        #pragma unroll
        for (int r = 0; r < 4; ++r) {
            float mv = mm[r];
            if (mv != mv) mv = 0.0f;
            float mx = mv;
            #pragma unroll
            for (int d = 1; d < 16; d <<= 1) mx = fmaxf(mx, __shfl_xor(mx, d));
            float e = __expf(mv - mx);
            float ss = e;
            #pragma unroll
            for (int d = 1; d < 16; d <<= 1) ss += __shfl_xor(ss, d);
            out[(size_t)(b0 + (lq << 2) + r) * 16 + l15] = e / ss;
        }
    }
}

extern "C" void kernel_launch(void* const* d_in, const int* in_sizes, int n_in,
                              void* d_out, int out_size, void* d_ws, size_t ws_size,
                              hipStream_t stream) {
    (void)in_sizes; (void)n_in; (void)out_size; (void)ws_size;
    const float* x     = (const float*)d_in[0];
    const float* w_in  = (const float*)d_in[1];
    const float* w_rec = (const float*)d_in[2];
    const float* w_out = (const float*)d_in[3];
    float* out = (float*)d_out;
    char* ws = (char*)d_ws;
    uint16_t* masks  = (uint16_t*)(ws + OFF_MASKS);
    uint16_t* win_s  = (uint16_t*)(ws + OFF_WIN);
    uint16_t* wrec_s = (uint16_t*)(ws + OFF_WREC);
    uint16_t* wout_s = (uint16_t*)(ws + OFF_WOUT);
    float* iin = (float*)(ws + OFF_IIN);

    k_prep  <<<dim3(16384), dim3(256), 0, stream>>>(x, masks);
    k_wsplit<<<dim3(4368),  dim3(256), 0, stream>>>(w_in, w_rec, w_out, win_s, wrec_s, wout_s);
    k_gemm  <<<dim3(512),   dim3(256), 0, stream>>>(masks, win_s, iin);
    k_scan  <<<dim3(128),   dim3(256), 0, stream>>>(iin, wrec_s, wout_s, out);
}